// Round 8
// baseline (135.897 us; speedup 1.0000x reference)
//
#include <hip/hip_runtime.h>
#include <math.h>

#define ORDER 32
#define TC 16

// h[b,t,d] = sum_{j=0}^{31} w[j] * x[b, t-31+j, d] + thr ; out = (h>=0) ? 1 : 0
// Each thread owns TWO d-columns (float2 loads/stores, 8B/lane) and TC time
// steps with a statically-indexed register window. Weights are read through
// uniform w[j] -> compiler scalarizes to s_load (SGPR operands in the FMA).
// f32 fast path + rare f64 recompute when |h| < 1e-3 (zero-flip requirement).
//
// NOTE: the zero-padding guard must be t0 >= ORDER-1 (NOT t0 != 0): with
// TC < ORDER-1, the t0=16 block reads t0-31 < 0 -> page fault (R4/R7 abort).
__global__ __launch_bounds__(256)
void psn_kernel(const float2* __restrict__ x,
                const float* __restrict__ w,
                const float* __restrict__ thr_p,
                float2* __restrict__ out)
{
    const int T = 1024, D2 = 512;                            // D/2 float2 cols
    const int d2 = blockIdx.x * blockDim.x + threadIdx.x;    // 0..511
    const int t0 = blockIdx.y * TC;
    const int b  = blockIdx.z;

    const float thr = thr_p[0];
    const size_t base = (size_t)b * T * D2 + d2;
    const float2* xb = x + base;
    float2*       ob = out + base;

    // Register window: xv[i] = x[b, t0-31+i, {2d,2d+1}], i in [0, TC+31)
    float2 xv[TC + ORDER - 1];
    if (t0 >= ORDER - 1) {
        const float2* p = xb + (size_t)(t0 - (ORDER - 1)) * D2;
        #pragma unroll
        for (int i = 0; i < TC + ORDER - 1; ++i)
            xv[i] = p[(size_t)i * D2];
    } else {
        #pragma unroll
        for (int i = 0; i < TC + ORDER - 1; ++i) {
            const int t = t0 - (ORDER - 1) + i;
            if (t >= 0) xv[i] = xb[(size_t)t * D2];
            else        { xv[i].x = 0.0f; xv[i].y = 0.0f; }
        }
    }

    #pragma unroll
    for (int tt = 0; tt < TC; ++tt) {
        float hx = thr, hy = thr;
        #pragma unroll
        for (int j = 0; j < ORDER; ++j) {
            const float wj = w[j];                 // uniform -> SGPR
            hx = fmaf(wj, xv[tt + j].x, hx);
            hy = fmaf(wj, xv[tt + j].y, hy);
        }

        float rx, ry;
        if (__builtin_expect(fabsf(hx) < 1e-3f || fabsf(hy) < 1e-3f, 0)) {
            // Boundary case: recompute in f64 (f32*f32 products exact in f64).
            double dx = (double)thr, dy = (double)thr;
            #pragma unroll
            for (int j = 0; j < ORDER; ++j) {
                dx = fma((double)w[j], (double)xv[tt + j].x, dx);
                dy = fma((double)w[j], (double)xv[tt + j].y, dy);
            }
            rx = (dx >= 0.0) ? 1.0f : 0.0f;
            ry = (dy >= 0.0) ? 1.0f : 0.0f;
        } else {
            rx = (hx >= 0.0f) ? 1.0f : 0.0f;
            ry = (hy >= 0.0f) ? 1.0f : 0.0f;
        }
        float2 r; r.x = rx; r.y = ry;
        ob[(size_t)(t0 + tt) * D2] = r;
    }
}

extern "C" void kernel_launch(void* const* d_in, const int* in_sizes, int n_in,
                              void* d_out, int out_size, void* d_ws, size_t ws_size,
                              hipStream_t stream)
{
    const float2* x  = (const float2*)d_in[0];
    const float* w   = (const float*)d_in[1];   // 32 taps
    const float* thr = (const float*)d_in[2];   // scalar (-1)
    float2* o = (float2*)d_out;

    dim3 grid(512 / 256, 1024 / TC, 16);        // (d2-tiles, t-chunks, B)
    psn_kernel<<<grid, 256, 0, stream>>>(x, w, thr, o);
}